// Round 4
// baseline (532.750 us; speedup 1.0000x reference)
//
#include <hip/hip_runtime.h>

#define N_NODES 100000
#define N_EDGES 625000
#define HIDDEN 128
#define NUM_GRAPHS 512
#define CAP 40   // max in-degree capacity; Poisson(6.25) => P(deg>40) ~ e-43

typedef unsigned int uint;
typedef unsigned short ushort;
typedef short v8s __attribute__((ext_vector_type(8)));
typedef float v16f __attribute__((ext_vector_type(16)));

__device__ __forceinline__ float b2f_lo(uint u) { return __uint_as_float(u << 16); }
__device__ __forceinline__ float b2f_hi(uint u) { return __uint_as_float(u & 0xffff0000u); }
__device__ __forceinline__ uint f2b(float f) {  // RNE f32 -> bf16 bits
  uint u = __float_as_uint(f);
  return (u + 0x7fffu + ((u >> 16) & 1u)) >> 16;
}

// ---------------- weight transpose+quantize: Wt[mat][n][k] bf16 ----------------
__global__ __launch_bounds__(256) void wtrans_k(const float* __restrict__ W1,
                                                const float* __restrict__ W2,
                                                ushort* __restrict__ Wt) {
  int mat = blockIdx.x;                       // 0..7 = layer*2 + which
  const float* W = ((mat & 1) ? W2 : W1) + (size_t)(mat >> 1) * 16384;
  ushort* o = Wt + (size_t)mat * 16384;
#pragma unroll
  for (int j = 0; j < 64; j++) {
    int idx = threadIdx.x + 256 * j;          // coalesced read W[k][n]
    int k = idx >> 7, n = idx & 127;
    o[n * 128 + k] = (ushort)f2b(W[idx]);
  }
}

// ---------------- embed: h[n][:] = bf16(node_emb[x[n]][:]) ----------------
__global__ __launch_bounds__(256) void embed_k(const int* __restrict__ x,
                                               const float* __restrict__ emb,
                                               ushort* __restrict__ h) {
  int t = blockIdx.x * 256 + threadIdx.x;     // one 8-col chunk per thread
  int n = t >> 4;
  if (n >= N_NODES) return;
  int c = t & 15;
  const float4* e = (const float4*)(emb + (size_t)x[n] * HIDDEN + c * 8);
  float4 a = e[0], b = e[1];
  uint4 o;
  o.x = f2b(a.x) | (f2b(a.y) << 16);
  o.y = f2b(a.z) | (f2b(a.w) << 16);
  o.z = f2b(b.x) | (f2b(b.y) << 16);
  o.w = f2b(b.z) | (f2b(b.w) << 16);
  ((uint4*)h)[t] = o;
}

// ---------------- build dst-keyed adjacency (per call) ----------------
__global__ __launch_bounds__(256) void build_k(const int* __restrict__ src,
                                               const int* __restrict__ dst,
                                               int* __restrict__ cursor,
                                               int* __restrict__ slots) {
  int e = blockIdx.x * 256 + threadIdx.x;
  if (e >= N_EDGES) return;
  int d = dst[e];
  int p = atomicAdd(&cursor[d], 1);
  if (p < CAP) slots[(size_t)d * CAP + p] = src[e];
}

// ---------------- gather: t0[n] = bf16( h[n] + sum_{e: dst=n} h[src[e]] ) ----------------
// 4-unrolled neighbor loop: int4 slot load + 4 independent row loads in flight
// (cuts the dependent-load chain from ~deg to ~deg/4).
__global__ __launch_bounds__(256) void gather_k(const ushort* __restrict__ h,
                                                const int* __restrict__ cursor,
                                                const int* __restrict__ slots,
                                                ushort* __restrict__ out) {
  int t = blockIdx.x * 256 + threadIdx.x;
  int n = t >> 4;
  if (n >= N_NODES) return;
  int c = t & 15;
  const uint4* H = (const uint4*)h;           // 16 uint4 per 128-col row
  uint4 v = H[n * 16 + c];
  float acc[8];
  acc[0] = b2f_lo(v.x); acc[1] = b2f_hi(v.x);
  acc[2] = b2f_lo(v.y); acc[3] = b2f_hi(v.y);
  acc[4] = b2f_lo(v.z); acc[5] = b2f_hi(v.z);
  acc[6] = b2f_lo(v.w); acc[7] = b2f_hi(v.w);
  int deg = cursor[n];
  if (deg > CAP) deg = CAP;
  const int* sl = slots + (size_t)n * CAP;
  int j = 0;
  for (; j + 4 <= deg; j += 4) {
    int4 sv = *(const int4*)(sl + j);         // 16B-aligned (CAP*4 and j*4 both %16==0)
    uint4 w0 = H[sv.x * 16 + c];
    uint4 w1 = H[sv.y * 16 + c];
    uint4 w2 = H[sv.z * 16 + c];
    uint4 w3 = H[sv.w * 16 + c];
    acc[0] += b2f_lo(w0.x); acc[1] += b2f_hi(w0.x);
    acc[2] += b2f_lo(w0.y); acc[3] += b2f_hi(w0.y);
    acc[4] += b2f_lo(w0.z); acc[5] += b2f_hi(w0.z);
    acc[6] += b2f_lo(w0.w); acc[7] += b2f_hi(w0.w);
    acc[0] += b2f_lo(w1.x); acc[1] += b2f_hi(w1.x);
    acc[2] += b2f_lo(w1.y); acc[3] += b2f_hi(w1.y);
    acc[4] += b2f_lo(w1.z); acc[5] += b2f_hi(w1.z);
    acc[6] += b2f_lo(w1.w); acc[7] += b2f_hi(w1.w);
    acc[0] += b2f_lo(w2.x); acc[1] += b2f_hi(w2.x);
    acc[2] += b2f_lo(w2.y); acc[3] += b2f_hi(w2.y);
    acc[4] += b2f_lo(w2.z); acc[5] += b2f_hi(w2.z);
    acc[6] += b2f_lo(w2.w); acc[7] += b2f_hi(w2.w);
    acc[0] += b2f_lo(w3.x); acc[1] += b2f_hi(w3.x);
    acc[2] += b2f_lo(w3.y); acc[3] += b2f_hi(w3.y);
    acc[4] += b2f_lo(w3.z); acc[5] += b2f_hi(w3.z);
    acc[6] += b2f_lo(w3.w); acc[7] += b2f_hi(w3.w);
  }
  for (; j < deg; j++) {
    int s = sl[j];
    uint4 w = H[s * 16 + c];
    acc[0] += b2f_lo(w.x); acc[1] += b2f_hi(w.x);
    acc[2] += b2f_lo(w.y); acc[3] += b2f_hi(w.y);
    acc[4] += b2f_lo(w.z); acc[5] += b2f_hi(w.z);
    acc[6] += b2f_lo(w.w); acc[7] += b2f_hi(w.w);
  }
  uint4 o;
  o.x = f2b(acc[0]) | (f2b(acc[1]) << 16);
  o.y = f2b(acc[2]) | (f2b(acc[3]) << 16);
  o.z = f2b(acc[4]) | (f2b(acc[5]) << 16);
  o.w = f2b(acc[6]) | (f2b(acc[7]) << 16);
  ((uint4*)out)[t] = o;
}

// ---------------- MFMA GEMM: out = [relu](A @ W + b), bf16 in, f32 acc ----------------
// 512 thr = 8 waves = 2 row-halves x 4 col-quarters; 128 rows/block.
// Per wave: B = 32 cols in 32 VGPRs, two 32-row A tiles prefetched (16 loads
// in flight), interleaved MFMA chains. ~148 VGPR -> 3 waves/SIMD.
// Never in-place (3-buffer rotation in launcher).
// MODE: 0 = bf16 out + relu, 1 = bf16 out, 2 = f32 out (last layer)
template <int MODE>
__global__ __launch_bounds__(512, 3) void gemm_bf16_k(const ushort* __restrict__ A,
                                                      const ushort* __restrict__ Wt,
                                                      const float* __restrict__ bias,
                                                      void* __restrict__ outv) {
  int tid = threadIdx.x;
  int lane = tid & 63;
  int wv = tid >> 6;                          // 0..7
  int rt = wv & 1;                            // row half
  int cq = wv >> 1;                           // col quarter
  int l31 = lane & 31;
  int khalf = lane >> 5;                      // which 8-wide k half
  int rowbase = blockIdx.x * 128 + rt * 64;

  union U { uint4 u; v8s s; };
  U B[8];                                     // 32 VGPRs
  const ushort* Wp = Wt + ((cq * 32 + l31) << 7) + khalf * 8;
#pragma unroll
  for (int ks = 0; ks < 8; ks++) B[ks].u = *(const uint4*)(Wp + ks * 16);

  float bv = bias[cq * 32 + l31];

  int r0 = rowbase + l31;      if (r0 >= N_NODES) r0 = N_NODES - 1;  // clamp; OOB never stored
  int r1 = rowbase + 32 + l31; if (r1 >= N_NODES) r1 = N_NODES - 1;
  const ushort* A0 = A + (size_t)r0 * HIDDEN + khalf * 8;
  const ushort* A1 = A + (size_t)r1 * HIDDEN + khalf * 8;
  U a0[8], a1[8];                             // 64 VGPRs, all loads in flight
#pragma unroll
  for (int ks = 0; ks < 8; ks++) a0[ks].u = *(const uint4*)(A0 + ks * 16);
#pragma unroll
  for (int ks = 0; ks < 8; ks++) a1[ks].u = *(const uint4*)(A1 + ks * 16);

  v16f acc0 = {}, acc1 = {};
#pragma unroll
  for (int ks = 0; ks < 8; ks++) {
    acc0 = __builtin_amdgcn_mfma_f32_32x32x16_bf16(a0[ks].s, B[ks].s, acc0, 0, 0, 0);
    acc1 = __builtin_amdgcn_mfma_f32_32x32x16_bf16(a1[ks].s, B[ks].s, acc1, 0, 0, 0);
  }

  // C/D layout (measured m74/m101): col = lane&31, row = (reg&3)+8*(reg>>2)+4*(lane>>5)
  int col = cq * 32 + l31;
  ushort* outb = (ushort*)outv;
  float* outf = (float*)outv;
#pragma unroll
  for (int tile = 0; tile < 2; tile++) {
    int rb = rowbase + tile * 32 + 4 * khalf;
#pragma unroll
    for (int r = 0; r < 16; r++) {
      int orow = rb + (r & 3) + 8 * (r >> 2);
      if (orow < N_NODES) {
        float vv = (tile ? acc1[r] : acc0[r]) + bv;
        if (MODE == 0) vv = fmaxf(vv, 0.f);
        if (MODE == 2) outf[(size_t)orow * HIDDEN + col] = vv;
        else           outb[(size_t)orow * HIDDEN + col] = (ushort)f2b(vv);
      }
    }
  }
}

// ---------------- pool (segmented, batch SORTED => no atomics), f32 in/out ----------------
__global__ __launch_bounds__(256) void pool_seg_k(const float* __restrict__ h,
                                                  const int* __restrict__ batch,
                                                  float* __restrict__ g) {
  __shared__ int se[2];
  __shared__ float4 red[8][32];
  int gi = blockIdx.x;
  int tid = threadIdx.x;
  if (tid < 2) {
    int target = gi + tid;                    // lower_bound(batch, target)
    int lo = 0, hi = N_NODES;
    while (lo < hi) {
      int mid = (lo + hi) >> 1;
      if (batch[mid] < target) lo = mid + 1; else hi = mid;
    }
    se[tid] = lo;
  }
  __syncthreads();
  int start = se[0], end = se[1];
  int cg = tid & 31, rg = tid >> 5;
  float4 acc = {0.f, 0.f, 0.f, 0.f};
  for (int r = start + rg; r < end; r += 8) {
    float4 v = ((const float4*)(h + (size_t)r * HIDDEN))[cg];
    acc.x += v.x; acc.y += v.y; acc.z += v.z; acc.w += v.w;
  }
  red[rg][cg] = acc;
  __syncthreads();
  if (rg == 0) {
    float4 s = red[0][cg];
#pragma unroll
    for (int i = 1; i < 8; i++) {
      float4 v = red[i][cg];
      s.x += v.x; s.y += v.y; s.z += v.z; s.w += v.w;
    }
    ((float4*)(g + (size_t)gi * HIDDEN))[cg] = s;
  }
}

// ---------------- final MLP: 128 -> 64 -> 32 -> 1, one block per graph ----------------
__global__ __launch_bounds__(64) void mlp_k(const float* __restrict__ g,
                                            const float* __restrict__ W1, const float* __restrict__ b1,
                                            const float* __restrict__ W2, const float* __restrict__ b2,
                                            const float* __restrict__ W3, const float* __restrict__ b3,
                                            float* __restrict__ out) {
  __shared__ float r1[128];
  __shared__ float r2[64];
  __shared__ float r3[32];
  int gi = blockIdx.x, t = threadIdx.x;
  r1[t] = g[(size_t)gi * 128 + t];
  r1[t + 64] = g[(size_t)gi * 128 + 64 + t];
  __syncthreads();
  float s = b1[t];
  for (int k = 0; k < 128; k++) s = fmaf(r1[k], W1[k * 64 + t], s);
  r2[t] = fmaxf(s, 0.f);
  __syncthreads();
  if (t < 32) {
    float s2 = b2[t];
    for (int k = 0; k < 64; k++) s2 = fmaf(r2[k], W2[k * 32 + t], s2);
    r3[t] = fmaxf(s2, 0.f);
  }
  __syncthreads();
  float pv = (t < 32) ? r3[t] * W3[t] : 0.f;
#pragma unroll
  for (int off = 32; off > 0; off >>= 1) pv += __shfl_down(pv, off);
  if (t == 0) out[gi] = pv + b3[0];
}

extern "C" void kernel_launch(void* const* d_in, const int* in_sizes, int n_in,
                              void* d_out, int out_size, void* d_ws, size_t ws_size,
                              hipStream_t stream) {
  const int* x = (const int*)d_in[0];
  const int* src = (const int*)d_in[1];
  const int* dst = src + N_EDGES;
  // d_in[2] = edge_attr, d_in[5] = edge_emb: computed-but-unused in reference
  const int* batch = (const int*)d_in[3];
  const float* node_emb = (const float*)d_in[4];
  const float* cW1 = (const float*)d_in[6];
  const float* cb1 = (const float*)d_in[7];
  const float* cW2 = (const float*)d_in[8];
  const float* cb2 = (const float*)d_in[9];
  const float* mW1 = (const float*)d_in[10];
  const float* mb1 = (const float*)d_in[11];
  const float* mW2 = (const float*)d_in[12];
  const float* mb2 = (const float*)d_in[13];
  const float* mW3 = (const float*)d_in[14];
  const float* mb3 = (const float*)d_in[15];
  float* out = (float*)d_out;

  char* p = (char*)d_ws;
  const size_t HB = (size_t)N_NODES * HIDDEN * sizeof(ushort);  // 25.6 MB
  ushort* h = (ushort*)p;      p += HB;
  ushort* t0 = (ushort*)p;     p += HB;
  ushort* t1 = (ushort*)p;     p += HB;
  float* hf = (float*)p;       p += (size_t)N_NODES * HIDDEN * sizeof(float);  // 51.2 MB
  ushort* Wtb = (ushort*)p;    p += (size_t)8 * 16384 * sizeof(ushort);
  int* cursor = (int*)p;       p += (size_t)N_NODES * sizeof(int);
  int* slots = (int*)p;        p += (size_t)N_NODES * CAP * sizeof(int);
  float* g = (float*)p;        p += (size_t)NUM_GRAPHS * HIDDEN * sizeof(float);

  hipMemsetAsync(cursor, 0, (size_t)N_NODES * sizeof(int), stream);
  wtrans_k<<<8, 256, 0, stream>>>(cW1, cW2, Wtb);
  embed_k<<<(N_NODES * 16 + 255) / 256, 256, 0, stream>>>(x, node_emb, h);
  build_k<<<(N_EDGES + 255) / 256, 256, 0, stream>>>(src, dst, cursor, slots);

  const int gemm_grid = (N_NODES + 127) / 128;  // 782
  for (int l = 0; l < 4; l++) {
    gather_k<<<(N_NODES * 16 + 255) / 256, 256, 0, stream>>>(h, cursor, slots, t0);
    gemm_bf16_k<0><<<gemm_grid, 512, 0, stream>>>(t0, Wtb + (size_t)(2 * l) * 16384,
                                                  cb1 + (size_t)l * HIDDEN, t1);
    if (l < 3) {
      gemm_bf16_k<1><<<gemm_grid, 512, 0, stream>>>(t1, Wtb + (size_t)(2 * l + 1) * 16384,
                                                    cb2 + (size_t)l * HIDDEN, h);
    } else {
      gemm_bf16_k<2><<<gemm_grid, 512, 0, stream>>>(t1, Wtb + (size_t)(2 * l + 1) * 16384,
                                                    cb2 + (size_t)l * HIDDEN, hf);
    }
  }

  pool_seg_k<<<NUM_GRAPHS, 256, 0, stream>>>(hf, batch, g);
  mlp_k<<<NUM_GRAPHS, 64, 0, stream>>>(g, mW1, mb1, mW2, mb2, mW3, mb3, out);
}

// Round 5
// 397.012 us; speedup vs baseline: 1.3419x; 1.3419x over previous
//
#include <hip/hip_runtime.h>

#define N_NODES 100000
#define N_EDGES 625000
#define HIDDEN 128
#define NUM_GRAPHS 512
#define CAP 40   // max in-degree capacity; Poisson(6.25) => P(deg>40) ~ e-43

typedef unsigned int uint;
typedef unsigned short ushort;
typedef short v8s __attribute__((ext_vector_type(8)));
typedef float v16f __attribute__((ext_vector_type(16)));

__device__ __forceinline__ float b2f_lo(uint u) { return __uint_as_float(u << 16); }
__device__ __forceinline__ float b2f_hi(uint u) { return __uint_as_float(u & 0xffff0000u); }
__device__ __forceinline__ uint f2b(float f) {  // RNE f32 -> bf16 bits
  uint u = __float_as_uint(f);
  return (u + 0x7fffu + ((u >> 16) & 1u)) >> 16;
}

// ---------------- weight transpose+quantize: Wt[mat][n][k] bf16 ----------------
__global__ __launch_bounds__(256) void wtrans_k(const float* __restrict__ W1,
                                                const float* __restrict__ W2,
                                                ushort* __restrict__ Wt) {
  int mat = blockIdx.x;                       // 0..7 = layer*2 + which
  const float* W = ((mat & 1) ? W2 : W1) + (size_t)(mat >> 1) * 16384;
  ushort* o = Wt + (size_t)mat * 16384;
#pragma unroll
  for (int j = 0; j < 64; j++) {
    int idx = threadIdx.x + 256 * j;          // coalesced read W[k][n]
    int k = idx >> 7, n = idx & 127;
    o[n * 128 + k] = (ushort)f2b(W[idx]);
  }
}

// ---------------- embed: h[n][:] = bf16(node_emb[x[n]][:]) ----------------
__global__ __launch_bounds__(256) void embed_k(const int* __restrict__ x,
                                               const float* __restrict__ emb,
                                               ushort* __restrict__ h) {
  int t = blockIdx.x * 256 + threadIdx.x;     // one 8-col chunk per thread
  int n = t >> 4;
  if (n >= N_NODES) return;
  int c = t & 15;
  const float4* e = (const float4*)(emb + (size_t)x[n] * HIDDEN + c * 8);
  float4 a = e[0], b = e[1];
  uint4 o;
  o.x = f2b(a.x) | (f2b(a.y) << 16);
  o.y = f2b(a.z) | (f2b(a.w) << 16);
  o.z = f2b(b.x) | (f2b(b.y) << 16);
  o.w = f2b(b.z) | (f2b(b.w) << 16);
  ((uint4*)h)[t] = o;
}

// ---------------- build dst-keyed adjacency (per call) ----------------
__global__ __launch_bounds__(256) void build_k(const int* __restrict__ src,
                                               const int* __restrict__ dst,
                                               int* __restrict__ cursor,
                                               int* __restrict__ slots) {
  int e = blockIdx.x * 256 + threadIdx.x;
  if (e >= N_EDGES) return;
  int d = dst[e];
  int p = atomicAdd(&cursor[d], 1);
  if (p < CAP) slots[(size_t)d * CAP + p] = src[e];
}

// ---------------- fused layer: h_out = (relu((agg+h)@W1+b1))@W2 + b2 ----------------
// Block = 256 thr = 4 waves, 128 rows. Each wave owns 32 rows end-to-end.
// Gather accumulates per-lane directly in MFMA A-frag layout (lane l31 = row,
// khalf = k-half; lanes l and l+32 pair on one node, consuming full 256B rows).
// W staged FRAGMENT-ORDERED in 32KB LDS (conflict-free ds_read_b128 B-frags),
// W1/W2 overlaid across barriers. z round-trips an 8KB/wave LDS patch written
// in A-frag order. LDS = 64KB -> 2 blocks/CU.
__device__ __forceinline__ void stageW(const ushort* __restrict__ Wt, uint4* Wf, int tid) {
  const uint4* s = (const uint4*)Wt;
#pragma unroll
  for (int i = 0; i < 8; i++) {
    int idx = tid + 256 * i;                  // 0..2047: n = idx>>4, 16B chunk j = idx&15
    int n = idx >> 4, j = idx & 15;
    // chunk j covers k = 8j..8j+7 -> ks = j>>1, khalf = j&1; frag slot:
    Wf[(((n >> 5) * 8 + (j >> 1)) << 6) + ((j & 1) << 5) + (n & 31)] = s[idx];
  }
}

__device__ __forceinline__ void acc_row(const uint4* __restrict__ rowp, int khalf,
                                        float acc[8][8]) {
  uint4 u[8];
#pragma unroll
  for (int ks = 0; ks < 8; ks++) u[ks] = rowp[khalf + 2 * ks];
#pragma unroll
  for (int ks = 0; ks < 8; ks++) {
    acc[ks][0] += b2f_lo(u[ks].x); acc[ks][1] += b2f_hi(u[ks].x);
    acc[ks][2] += b2f_lo(u[ks].y); acc[ks][3] += b2f_hi(u[ks].y);
    acc[ks][4] += b2f_lo(u[ks].z); acc[ks][5] += b2f_hi(u[ks].z);
    acc[ks][6] += b2f_lo(u[ks].w); acc[ks][7] += b2f_hi(u[ks].w);
  }
}

__global__ __launch_bounds__(256, 2) void layer_k(const ushort* __restrict__ hin,
                                                  const int* __restrict__ cursor,
                                                  const int* __restrict__ slots,
                                                  const ushort* __restrict__ W1t,
                                                  const ushort* __restrict__ W2t,
                                                  const float* __restrict__ b1,
                                                  const float* __restrict__ b2,
                                                  ushort* __restrict__ hout) {
  __shared__ uint4 Wf[2048];                  // 32 KB, W1 then overlaid W2
  __shared__ ushort zbuf[4 * 4096];           // 8 KB per wave

  int tid = threadIdx.x;
  int lane = tid & 63;
  int wv = tid >> 6;
  int l31 = lane & 31;
  int khalf = lane >> 5;
  int row = blockIdx.x * 128 + wv * 32 + l31;
  int arow = row < N_NODES ? row : N_NODES - 1;

  float bv1[4], bv2[4];
#pragma unroll
  for (int c = 0; c < 4; c++) { bv1[c] = b1[c * 32 + l31]; bv2[c] = b2[c * 32 + l31]; }

  stageW(W1t, Wf, tid);

  // ---- gather phase: acc[ks][e] = f32 sum over self + neighbors ----
  float acc[8][8];
#pragma unroll
  for (int ks = 0; ks < 8; ks++)
#pragma unroll
    for (int e = 0; e < 8; e++) acc[ks][e] = 0.f;

  const uint4* base = (const uint4*)hin;      // 16 uint4 per 128-col row
  acc_row(base + (size_t)arow * 16, khalf, acc);   // self term
  int deg = (row < N_NODES) ? cursor[row] : 0;
  if (deg > CAP) deg = CAP;
  const int* sl = slots + (size_t)arow * CAP;
  int s = (deg > 0) ? sl[0] : 0;
  for (int j = 0; j < deg; j++) {
    int snext = (j + 1 < deg) ? sl[j + 1] : 0;  // prefetch next slot
    acc_row(base + (size_t)s * 16, khalf, acc);
    s = snext;
  }

  // round to bf16 A-frags (same rounding point as unfused t0 = bf16(agg+h))
  union U { uint4 u; v8s s; };
  U afr[8];
#pragma unroll
  for (int ks = 0; ks < 8; ks++) {
    afr[ks].u.x = f2b(acc[ks][0]) | (f2b(acc[ks][1]) << 16);
    afr[ks].u.y = f2b(acc[ks][2]) | (f2b(acc[ks][3]) << 16);
    afr[ks].u.z = f2b(acc[ks][4]) | (f2b(acc[ks][5]) << 16);
    afr[ks].u.w = f2b(acc[ks][6]) | (f2b(acc[ks][7]) << 16);
  }

  __syncthreads();                            // W1 staged

  // ---- GEMM1: z = relu(A@W1 + b1) ----
  v16f acc1[4] = {};
#pragma unroll
  for (int c = 0; c < 4; c++)
#pragma unroll
    for (int ks = 0; ks < 8; ks++) {
      U b; b.u = Wf[((c * 8 + ks) << 6) + lane];
      acc1[c] = __builtin_amdgcn_mfma_f32_32x32x16_bf16(afr[ks].s, b.s, acc1[c], 0, 0, 0);
    }

  // write z to per-wave LDS patch in A-frag order.
  // C/D layout: col = c*32+l31, local row = (r&3)+8*(r>>2)+4*khalf
  ushort* zb = zbuf + (wv << 12);
#pragma unroll
  for (int c = 0; c < 4; c++) {
    int col = c * 32 + l31;
    int zoff = ((col >> 4) << 9) + (((col >> 3) & 1) << 8) + (col & 7);  // (ks'*64 + kh'*32)*8 + e
#pragma unroll
    for (int r = 0; r < 16; r++) {
      int orow = (r & 3) + 8 * (r >> 2) + 4 * khalf;
      float v = fmaxf(acc1[c][r] + bv1[c], 0.f);
      zb[zoff + orow * 8] = (ushort)f2b(v);
    }
  }

  __syncthreads();                            // all gemm1 B-reads + z-writes done
  stageW(W2t, Wf, tid);                       // overlay W2
  __syncthreads();

  // ---- GEMM2: h_out = z@W2 + b2 ----
  U az[8];
#pragma unroll
  for (int ks = 0; ks < 8; ks++)
    az[ks].u = *(const uint4*)(zb + ((ks << 6) + lane) * 8);   // conflict-free b128

  v16f acc2[4] = {};
#pragma unroll
  for (int c = 0; c < 4; c++)
#pragma unroll
    for (int ks = 0; ks < 8; ks++) {
      U b; b.u = Wf[((c * 8 + ks) << 6) + lane];
      acc2[c] = __builtin_amdgcn_mfma_f32_32x32x16_bf16(az[ks].s, b.s, acc2[c], 0, 0, 0);
    }

  int rbase = blockIdx.x * 128 + wv * 32 + 4 * khalf;
#pragma unroll
  for (int c = 0; c < 4; c++) {
    int col = c * 32 + l31;
#pragma unroll
    for (int r = 0; r < 16; r++) {
      int orow = rbase + (r & 3) + 8 * (r >> 2);
      if (orow < N_NODES)
        hout[(size_t)orow * HIDDEN + col] = (ushort)f2b(acc2[c][r] + bv2[c]);
    }
  }
}

// ---------------- fused pool+MLP: g = segsum(h); out = mlp(g) ----------------
__global__ __launch_bounds__(256) void poolmlp_k(const ushort* __restrict__ h,
                                                 const int* __restrict__ batch,
                                                 const float* __restrict__ W1, const float* __restrict__ b1,
                                                 const float* __restrict__ W2, const float* __restrict__ b2,
                                                 const float* __restrict__ W3, const float* __restrict__ b3,
                                                 float* __restrict__ out) {
  __shared__ int se[2];
  __shared__ float red[16][16][8];
  __shared__ float gl[128];
  __shared__ float r2[64];
  __shared__ float r3[32];
  int gi = blockIdx.x, tid = threadIdx.x;
  if (tid < 2) {
    int target = gi + tid;                    // lower_bound(batch, target)
    int lo = 0, hi = N_NODES;
    while (lo < hi) {
      int mid = (lo + hi) >> 1;
      if (batch[mid] < target) lo = mid + 1; else hi = mid;
    }
    se[tid] = lo;
  }
  __syncthreads();
  int start = se[0], end = se[1];
  int cg = tid & 15, rg = tid >> 4;
  float acc[8] = {0.f, 0.f, 0.f, 0.f, 0.f, 0.f, 0.f, 0.f};
  for (int r = start + rg; r < end; r += 16) {
    uint4 v = ((const uint4*)h)[r * 16 + cg];
    acc[0] += b2f_lo(v.x); acc[1] += b2f_hi(v.x);
    acc[2] += b2f_lo(v.y); acc[3] += b2f_hi(v.y);
    acc[4] += b2f_lo(v.z); acc[5] += b2f_hi(v.z);
    acc[6] += b2f_lo(v.w); acc[7] += b2f_hi(v.w);
  }
#pragma unroll
  for (int j = 0; j < 8; j++) red[rg][cg][j] = acc[j];
  __syncthreads();
  if (rg == 0) {
    float s[8];
#pragma unroll
    for (int j = 0; j < 8; j++) s[j] = red[0][cg][j];
#pragma unroll
    for (int i = 1; i < 16; i++)
#pragma unroll
      for (int j = 0; j < 8; j++) s[j] += red[i][cg][j];
#pragma unroll
    for (int j = 0; j < 8; j++) gl[cg * 8 + j] = s[j];
  }
  __syncthreads();
  if (tid < 64) {
    float s = b1[tid];
    for (int k = 0; k < 128; k++) s = fmaf(gl[k], W1[k * 64 + tid], s);
    r2[tid] = fmaxf(s, 0.f);
  }
  __syncthreads();
  if (tid < 32) {
    float s2 = b2[tid];
    for (int k = 0; k < 64; k++) s2 = fmaf(r2[k], W2[k * 32 + tid], s2);
    r3[tid] = fmaxf(s2, 0.f);
  }
  __syncthreads();
  if (tid < 64) {
    float pv = (tid < 32) ? r3[tid] * W3[tid] : 0.f;
#pragma unroll
    for (int off = 32; off > 0; off >>= 1) pv += __shfl_down(pv, off);
    if (tid == 0) out[gi] = pv + b3[0];
  }
}

extern "C" void kernel_launch(void* const* d_in, const int* in_sizes, int n_in,
                              void* d_out, int out_size, void* d_ws, size_t ws_size,
                              hipStream_t stream) {
  const int* x = (const int*)d_in[0];
  const int* src = (const int*)d_in[1];
  const int* dst = src + N_EDGES;
  // d_in[2] = edge_attr, d_in[5] = edge_emb: computed-but-unused in reference
  const int* batch = (const int*)d_in[3];
  const float* node_emb = (const float*)d_in[4];
  const float* cW1 = (const float*)d_in[6];
  const float* cb1 = (const float*)d_in[7];
  const float* cW2 = (const float*)d_in[8];
  const float* cb2 = (const float*)d_in[9];
  const float* mW1 = (const float*)d_in[10];
  const float* mb1 = (const float*)d_in[11];
  const float* mW2 = (const float*)d_in[12];
  const float* mb2 = (const float*)d_in[13];
  const float* mW3 = (const float*)d_in[14];
  const float* mb3 = (const float*)d_in[15];
  float* out = (float*)d_out;

  char* p = (char*)d_ws;
  const size_t HB = (size_t)N_NODES * HIDDEN * sizeof(ushort);  // 25.6 MB
  ushort* h = (ushort*)p;      p += HB;
  ushort* t0 = (ushort*)p;     p += HB;
  ushort* Wtb = (ushort*)p;    p += (size_t)8 * 16384 * sizeof(ushort);
  int* cursor = (int*)p;       p += (size_t)N_NODES * sizeof(int);
  int* slots = (int*)p;        p += (size_t)N_NODES * CAP * sizeof(int);

  hipMemsetAsync(cursor, 0, (size_t)N_NODES * sizeof(int), stream);
  wtrans_k<<<8, 256, 0, stream>>>(cW1, cW2, Wtb);
  embed_k<<<(N_NODES * 16 + 255) / 256, 256, 0, stream>>>(x, node_emb, h);
  build_k<<<(N_EDGES + 255) / 256, 256, 0, stream>>>(src, dst, cursor, slots);

  const int grid = (N_NODES + 127) / 128;  // 782
  ushort* bufs[2] = {h, t0};
  for (int l = 0; l < 4; l++) {
    layer_k<<<grid, 256, 0, stream>>>(bufs[l & 1], cursor, slots,
                                      Wtb + (size_t)(2 * l) * 16384,
                                      Wtb + (size_t)(2 * l + 1) * 16384,
                                      cb1 + (size_t)l * HIDDEN,
                                      cb2 + (size_t)l * HIDDEN,
                                      bufs[(l & 1) ^ 1]);
  }
  // after 4 layers output is back in h (bufs[0])
  poolmlp_k<<<NUM_GRAPHS, 256, 0, stream>>>(h, batch, mW1, mb1, mW2, mb2, mW3, mb3, out);
}